// Round 18
// baseline (241.263 us; speedup 1.0000x reference)
//
#include <hip/hip_runtime.h>
#include <hip/hip_bf16.h>

// WeightedLoss round 18: r17 (staged gram via global_load_lds on the packed
// layout) with the sim-park bounds bug fixed. r17's simW used stride 17 but
// the 64x64 wave tile parks 32 u32/thread (indices 0..31): inter-thread slot
// overlap + OOB write into rP -> absmax 0.3125. Now stride 33 (odd -> lanes
// hit distinct banks each step; 32 < 33; no OOB). Staged gram unchanged:
// K=64 slices, 8 zero-VGPR global_load_lds per thread per slice, 128 MFMAs
// per block-slice between barrier pairs.
// ws: [0] Obp bf16 packed 4 MB | [4194304] Lnp bf16 packed 2 MB
//     [6291456] sq f32 | [6324224] pos_sums | [6356992] neg_sums
//     [6389760] stats u32[3]

#define B_N 8192
#define NT   64
#define TILE 128
#define NTRI 2080

typedef __attribute__((ext_vector_type(8))) short bf16x8;
typedef __attribute__((ext_vector_type(4))) float f32x4;
typedef __attribute__((ext_vector_type(2))) _Float16 f16x2;

typedef const __attribute__((address_space(1))) void g_void;
typedef __attribute__((address_space(3))) void l_void;

__device__ __forceinline__ unsigned fenc(float f) {
    unsigned u = __float_as_uint(f);
    return (u & 0x80000000u) ? ~u : (u | 0x80000000u);
}
__device__ __forceinline__ float fdec(unsigned k) {
    unsigned u = (k & 0x80000000u) ? (k ^ 0x80000000u) : ~k;
    return __uint_as_float(u);
}
__device__ __forceinline__ unsigned pack2(float a, float b) {
    f16x2 p; p[0] = (_Float16)a; p[1] = (_Float16)b;
    return *(unsigned*)&p;
}

// Supertile decode: 4 diagonal 16x16-tri supertiles (136 tiles, b<544),
// then 6 off-diagonal 16x16 supertiles (256 tiles each). bi<=bj always.
__device__ __forceinline__ void tile_decode(int b, int& bi, int& bj) {
    int si, sj, ti, tj;
    if (b < 544) {
        int sb = b / 136, w = b - sb * 136;
        int i = 0;
        while (w >= 16 - i) { w -= 16 - i; i++; }
        si = sb; sj = sb; ti = i; tj = i + w;
    } else {
        int q = (b - 544) >> 8, w = (b - 544) & 255;
        int i = 0;
        while (q >= 3 - i) { q -= 3 - i; i++; }
        si = i; sj = i + 1 + q;
        ti = w >> 4; tj = w & 15;
    }
    bi = si * 16 + ti; bj = sj * 16 + tj;
}

// ---------------------------------------------------------------- prep ----
// One block per 16-row group g. LDS transpose -> contiguous packed writes.
// Packed layout: 16-B slot S = (g*(K/8) + o)*16 + r holds X[g*16+r][o*8..+7].
__global__ __launch_bounds__(256) void prep_kernel(
    const float* __restrict__ outputs, const float* __restrict__ labels,
    __hip_bfloat16* __restrict__ Obp, __hip_bfloat16* __restrict__ Lnp,
    float* __restrict__ sq, float* __restrict__ pos_sums,
    float* __restrict__ neg_sums, unsigned* __restrict__ stats) {
    int g = blockIdx.x, tid = threadIdx.x;
    int rl = tid >> 4, c = tid & 15;
    int row = g * 16 + rl;
    __shared__ __align__(16) short tO[16][264];
    __shared__ __align__(16) short tL[16][136];

    float s = 0.f;
    #pragma unroll
    for (int k = 0; k < 4; k++) {
        f32x4 v = *(const f32x4*)&outputs[(size_t)row * 256 + c * 16 + k * 4];
        s += v[0]*v[0] + v[1]*v[1] + v[2]*v[2] + v[3]*v[3];
        __hip_bfloat16 b4[4];
        #pragma unroll
        for (int i = 0; i < 4; i++) b4[i] = __float2bfloat16(v[i]);
        *(uint2*)&tO[rl][c * 16 + k * 4] = *(uint2*)b4;
    }
    #pragma unroll
    for (int m = 1; m < 16; m <<= 1) s += __shfl_xor(s, m);
    if (c == 0) sq[row] = s;

    float ls = 0.f;
    f32x4 u0 = *(const f32x4*)&labels[(size_t)row * 128 + c * 8];
    f32x4 u1 = *(const f32x4*)&labels[(size_t)row * 128 + c * 8 + 4];
    ls += u0[0]*u0[0] + u0[1]*u0[1] + u0[2]*u0[2] + u0[3]*u0[3];
    ls += u1[0]*u1[0] + u1[1]*u1[1] + u1[2]*u1[2] + u1[3]*u1[3];
    #pragma unroll
    for (int m = 1; m < 16; m <<= 1) ls += __shfl_xor(ls, m);
    float inv = 1.f / (sqrtf(ls) + 1e-12f);
    {
        __hip_bfloat16 b4[4];
        #pragma unroll
        for (int i = 0; i < 4; i++) b4[i] = __float2bfloat16(u0[i] * inv);
        *(uint2*)&tL[rl][c * 8] = *(uint2*)b4;
        #pragma unroll
        for (int i = 0; i < 4; i++) b4[i] = __float2bfloat16(u1[i] * inv);
        *(uint2*)&tL[rl][c * 8 + 4] = *(uint2*)b4;
    }
    if (tid < 16) { pos_sums[g * 16 + tid] = 0.f; neg_sums[g * 16 + tid] = 0.f; }
    if (g == 0 && tid == 0) {
        stats[0] = 0xFFFFFFFFu; stats[1] = 0u; stats[2] = 0u;
    }
    __syncthreads();

    #pragma unroll
    for (int q = 0; q < 2; q++) {
        int sl = tid * 2 + q;
        int o = sl >> 4, rr = sl & 15;
        uint4 d = *(uint4*)&tO[rr][o * 8];
        *(uint4*)&Obp[(size_t)g * 4096 + (size_t)sl * 8] = d;
    }
    {
        int o = tid >> 4, rr = tid & 15;
        uint4 d = *(uint4*)&tL[rr][o * 8];
        *(uint4*)&Lnp[(size_t)g * 2048 + (size_t)tid * 8] = d;
    }
}

// ------------------------------------------------- staged slice gram ----
// Stage a K=64 slice (o-range [o0,o0+8)) of 8 packed row-groups starting at
// group g0 into LDS tile L (1024 x 16-B units, linear). 4 global_load_lds
// per thread; unit u = p*256+tid -> gl=u>>7, off=u&127; source slot
// ((g0+gl)*KD8 + o0)*16 + off is contiguous per 128-unit run -> coalesced.
template<int KD8>
__device__ __forceinline__ void stage_slice(
    const short* __restrict__ P, int g0, int o0, short* L, int tid) {
    #pragma unroll
    for (int p = 0; p < 4; p++) {
        int u = p * 256 + tid;
        int gl = u >> 7, off = u & 127;
        size_t gu = ((size_t)(g0 + gl) * KD8 + o0) * 16 + off;
        __builtin_amdgcn_global_load_lds((g_void*)(P + gu * 8),
                                         (l_void*)(L + (size_t)u * 8), 16, 0, 0);
    }
}

// 32 MFMAs per wave over one staged K=64 slice pair (64x64 wave tile).
// Fragment (mi,kc): LDS unit (wm4+mi)*128 + (kc*4+quad)*16 + l15.
__device__ __forceinline__ void mfma_slice(
    const short* As, const short* Bs, int wm4, int wn4,
    int l15, int quad, f32x4 (&acc)[4][4]) {
    #pragma unroll
    for (int kc = 0; kc < 2; kc++) {
        bf16x8 a[4], b[4];
        #pragma unroll
        for (int mi = 0; mi < 4; mi++)
            a[mi] = *(const bf16x8*)&As[((wm4 + mi) * 128
                                         + (kc * 4 + quad) * 16 + l15) * 8];
        #pragma unroll
        for (int ni = 0; ni < 4; ni++)
            b[ni] = *(const bf16x8*)&Bs[((wn4 + ni) * 128
                                         + (kc * 4 + quad) * 16 + l15) * 8];
        #pragma unroll
        for (int mi = 0; mi < 4; mi++)
            #pragma unroll
            for (int ni = 0; ni < 4; ni++)
                acc[mi][ni] = __builtin_amdgcn_mfma_f32_16x16x32_bf16(
                    a[mi], b[ni], acc[mi][ni], 0, 0, 0);
    }
}

__device__ __forceinline__ void zero_acc(f32x4 (&acc)[4][4]) {
    #pragma unroll
    for (int mi = 0; mi < 4; mi++)
        #pragma unroll
        for (int ni = 0; ni < 4; ni++) {
            f32x4 z = {0.f, 0.f, 0.f, 0.f};
            acc[mi][ni] = z;
        }
}

// Full gram over NS slices: barrier / stage / barrier / mfma per slice.
template<int KD8, int NS>
__device__ __forceinline__ void gram_staged(
    const short* __restrict__ P, int gA0, int gB0,
    short* As, short* Bs, int tid, int wm4, int wn4,
    int l15, int quad, f32x4 (&acc)[4][4]) {
    #pragma unroll
    for (int s = 0; s < NS; s++) {
        __syncthreads();                 // previous slice's reads done
        stage_slice<KD8>(P, gA0, s * 8, As, tid);
        stage_slice<KD8>(P, gB0, s * 8, Bs, tid);
        __syncthreads();                 // staging drained
        mfma_slice(As, Bs, wm4, wn4, l15, quad, acc);
    }
}

// ---------------------------------------------------------------- stats ----
__global__ __launch_bounds__(256, 2) void stats_kernel(
    const short* __restrict__ Lnp, const short* __restrict__ Obp,
    const float* __restrict__ sq, unsigned* __restrict__ stats) {
    int bi, bj;
    tile_decode(blockIdx.x, bi, bj);
    int tid = threadIdx.x, lane = tid & 63, wid = tid >> 6;
    int wm = (wid >> 1) * 64, wn = (wid & 1) * 64;
    int wm4 = (wid >> 1) * 4, wn4 = (wid & 1) * 4;
    int l15 = lane & 15, quad = lane >> 4;
    int rB = bi * TILE, cB = bj * TILE;

    __shared__ __align__(16) short As[1024 * 8];   // 16 KB
    __shared__ __align__(16) short Bs[1024 * 8];   // 16 KB

    float lmin = 1e30f, lmax = -1e30f, dmax = 0.f;
    f32x4 acc[4][4];

    zero_acc(acc);
    gram_staged<16, 2>(Lnp, bi * 8, bj * 8, As, Bs, tid, wm4, wn4, l15, quad, acc);
    #pragma unroll
    for (int mi = 0; mi < 4; mi++)
        #pragma unroll
        for (int ni = 0; ni < 4; ni++)
            #pragma unroll
            for (int r = 0; r < 4; r++) {
                float s = acc[mi][ni][r];
                lmin = fminf(lmin, s);
                lmax = fmaxf(lmax, s);
            }

    zero_acc(acc);
    gram_staged<32, 4>(Obp, bi * 8, bj * 8, As, Bs, tid, wm4, wn4, l15, quad, acc);
    float sqj[4];
    #pragma unroll
    for (int ni = 0; ni < 4; ni++) sqj[ni] = sq[cB + wn + ni * 16 + l15];
    #pragma unroll
    for (int mi = 0; mi < 4; mi++) {
        f32x4 sqi = *(const f32x4*)&sq[rB + wm + mi * 16 + quad * 4];
        #pragma unroll
        for (int r = 0; r < 4; r++)
            #pragma unroll
            for (int ni = 0; ni < 4; ni++) {
                float d2 = fmaxf(sqi[r] + sqj[ni] - 2.f * acc[mi][ni][r], 0.f);
                dmax = fmaxf(dmax, d2);
            }
    }

    #pragma unroll
    for (int m = 1; m < 64; m <<= 1) {
        lmin = fminf(lmin, __shfl_xor(lmin, m));
        lmax = fmaxf(lmax, __shfl_xor(lmax, m));
        dmax = fmaxf(dmax, __shfl_xor(dmax, m));
    }
    __shared__ float red[3][4];
    if ((tid & 63) == 0) { red[0][wid] = lmin; red[1][wid] = lmax; red[2][wid] = dmax; }
    __syncthreads();
    if (tid == 0) {
        lmin = fminf(fminf(red[0][0], red[0][1]), fminf(red[0][2], red[0][3]));
        lmax = fmaxf(fmaxf(red[1][0], red[1][1]), fmaxf(red[1][2], red[1][3]));
        dmax = fmaxf(fmaxf(red[2][0], red[2][1]), fmaxf(red[2][2], red[2][3]));
        atomicMin(&stats[0], fenc(lmin));
        atomicMax(&stats[1], fenc(lmax));
        atomicMax(&stats[2], fenc(dmax));
    }
}

// ----------------------------------------------------------------- loss ----
// Staged gram S -> park raw sim in private LDS slot (32 u32/lane, stride 33:
// no overlap, odd stride -> distinct banks per step; same-thread read-back,
// no barrier needed) -> staged gram G into SAME acc regs -> fused epilogue.
__global__ __launch_bounds__(256, 2) void loss_kernel(
    const short* __restrict__ Lnp, const short* __restrict__ Obp,
    const float* __restrict__ sq, const unsigned* __restrict__ stats,
    float* __restrict__ pos_sums, float* __restrict__ neg_sums) {
    int bi, bj;
    tile_decode(blockIdx.x, bi, bj);
    int tid = threadIdx.x, lane = tid & 63, wid = tid >> 6;
    int wm = (wid >> 1) * 64, wn = (wid & 1) * 64;
    int wm4 = (wid >> 1) * 4, wn4 = (wid & 1) * 4;
    int l15 = lane & 15, quad = lane >> 4;
    int rB = bi * TILE, cB = bj * TILE;

    __shared__ __align__(16) short As[1024 * 8];   // 16 KB
    __shared__ __align__(16) short Bs[1024 * 8];   // 16 KB
    __shared__ unsigned simW[256 * 33];            // 33 KB: 32 u32 used/thread
    __shared__ float rP[TILE][2], rN[TILE][2];
    __shared__ float cP[TILE][2], cN[TILE][2];
    unsigned* my = &simW[tid * 33];

    f32x4 acc[4][4];

    zero_acc(acc);
    gram_staged<16, 2>(Lnp, bi * 8, bj * 8, As, Bs, tid, wm4, wn4, l15, quad, acc);
    #pragma unroll
    for (int mi = 0; mi < 4; mi++)
        #pragma unroll
        for (int ni = 0; ni < 4; ni++) {
            my[(mi * 4 + ni) * 2 + 0] = pack2(acc[mi][ni][0], acc[mi][ni][1]);
            my[(mi * 4 + ni) * 2 + 1] = pack2(acc[mi][ni][2], acc[mi][ni][3]);
        }

    zero_acc(acc);
    gram_staged<32, 4>(Obp, bi * 8, bj * 8, As, Bs, tid, wm4, wn4, l15, quad, acc);

    float smin = fdec(stats[0]);
    float smax = fdec(stats[1]);
    float d2max = fdec(stats[2]);
    float invr = 1.f / (smax - smin);
    float invem = rsqrtf(d2max);

    float sqj[4];
    #pragma unroll
    for (int ni = 0; ni < 4; ni++) sqj[ni] = sq[cB + wn + ni * 16 + l15];
    float cpsum[4] = {0.f, 0.f, 0.f, 0.f};
    float cnsum[4] = {0.f, 0.f, 0.f, 0.f};

    #pragma unroll
    for (int mi = 0; mi < 4; mi++) {
        f32x4 sqi = *(const f32x4*)&sq[rB + wm + mi * 16 + quad * 4];
        float ps[4] = {0.f, 0.f, 0.f, 0.f};
        float ns[4] = {0.f, 0.f, 0.f, 0.f};
        #pragma unroll
        for (int ni = 0; ni < 4; ni++) {
            f16x2 s01 = ((const f16x2*)my)[(mi * 4 + ni) * 2 + 0];
            f16x2 s23 = ((const f16x2*)my)[(mi * 4 + ni) * 2 + 1];
            #pragma unroll
            for (int r = 0; r < 4; r++) {
                float sraw = (r < 2) ? (float)s01[r] : (float)s23[r - 2];
                float sn = (sraw - smin) * invr;
                float g = acc[mi][ni][r];
                float d2 = fmaxf(sqi[r] + sqj[ni] - 2.f * g, 0.f);
                float eud = (d2 > 0.f) ? sqrtf(d2) * invem : 0.f;
                float dist = eud + sn;
                bool pos = sn > 0.5f;   // TAU
                float pv = pos ? __expf(dist) : 0.f;
                float nv = pos ? 0.f : __expf(1.0f - dist);  // MAG = 1
                ps[r] += pv;  ns[r] += nv;
                cpsum[ni] += pv;  cnsum[ni] += nv;
            }
        }
        #pragma unroll
        for (int r = 0; r < 4; r++) {
            #pragma unroll
            for (int m = 1; m < 16; m <<= 1) {
                ps[r] += __shfl_xor(ps[r], m);
                ns[r] += __shfl_xor(ns[r], m);
            }
            if (l15 == 0) {
                int rr = wm + mi * 16 + quad * 4 + r;
                rP[rr][wid & 1] = ps[r];
                rN[rr][wid & 1] = ns[r];
            }
        }
    }
    #pragma unroll
    for (int ni = 0; ni < 4; ni++) {
        #pragma unroll
        for (int m = 16; m < 64; m <<= 1) {
            cpsum[ni] += __shfl_xor(cpsum[ni], m);
            cnsum[ni] += __shfl_xor(cnsum[ni], m);
        }
        if (quad == 0) {
            int cc = wn + ni * 16 + l15;
            cP[cc][wid >> 1] = cpsum[ni];
            cN[cc][wid >> 1] = cnsum[ni];
        }
    }
    __syncthreads();
    if (tid < TILE) {
        atomicAdd(&pos_sums[bi * TILE + tid], rP[tid][0] + rP[tid][1]);
        atomicAdd(&neg_sums[bi * TILE + tid], rN[tid][0] + rN[tid][1]);
        if (bi != bj) {
            atomicAdd(&pos_sums[bj * TILE + tid], cP[tid][0] + cP[tid][1]);
            atomicAdd(&neg_sums[bj * TILE + tid], cN[tid][0] + cN[tid][1]);
        }
    }
}

// ------------------------------------------------------------- finalize ----
__global__ __launch_bounds__(256) void finalize_kernel(
    const float* __restrict__ pos_sums, const float* __restrict__ neg_sums,
    float* __restrict__ out) {
    int t = threadIdx.x;
    float acc = 0.f;
    for (int i = t; i < B_N; i += 256) {
        float p = pos_sums[i], n = neg_sums[i];
        float pl = fmaxf(logf(p), 0.f);
        float nl = (n > 0.f) ? fmaxf(logf(n), 0.f) : 0.f;
        acc += pl + nl;
    }
    #pragma unroll
    for (int m = 1; m < 64; m <<= 1) acc += __shfl_xor(acc, m);
    __shared__ float w4[4];
    if ((t & 63) == 0) w4[t >> 6] = acc;
    __syncthreads();
    if (t == 0) out[0] = (w4[0] + w4[1] + w4[2] + w4[3]) / (float)B_N;
}

// ------------------------------------------------------------------ entry ----
extern "C" void kernel_launch(void* const* d_in, const int* in_sizes, int n_in,
                              void* d_out, int out_size, void* d_ws, size_t ws_size,
                              hipStream_t stream) {
    const float* outputs = (const float*)d_in[0];
    const float* labels  = (const float*)d_in[1];
    float* out = (float*)d_out;
    char* ws = (char*)d_ws;
    __hip_bfloat16* Obp = (__hip_bfloat16*)(ws);
    __hip_bfloat16* Lnp = (__hip_bfloat16*)(ws + 4194304);
    float* sq           = (float*)(ws + 6291456);
    float* pos_sums     = (float*)(ws + 6324224);
    float* neg_sums     = (float*)(ws + 6356992);
    unsigned* stats     = (unsigned*)(ws + 6389760);

    prep_kernel<<<B_N / 16, 256, 0, stream>>>(outputs, labels, Obp, Lnp, sq,
                                              pos_sums, neg_sums, stats);
    stats_kernel<<<NTRI, 256, 0, stream>>>((const short*)Lnp, (const short*)Obp,
                                           sq, stats);
    loss_kernel<<<NTRI, 256, 0, stream>>>((const short*)Lnp, (const short*)Obp,
                                          sq, stats, pos_sums, neg_sums);
    finalize_kernel<<<1, 256, 0, stream>>>(pos_sums, neg_sums, out);
}

// Round 19
// 206.329 us; speedup vs baseline: 1.1693x; 1.1693x over previous
//
#include <hip/hip_runtime.h>
#include <hip/hip_bf16.h>

// WeightedLoss round 19: cut gram passes 4 -> 2. Eighteen rounds show any
// gram-pass kernel costs ~85-90 us regardless of structure (latency+barrier
// bound, MFMA floor 11 us). So: stats (r18's staged gram, clean counters)
// now ALSO materializes fp16 sim/eud in r7's verified chunked-coalesced NT
// layout (139 MB full-line fire-and-forget stores), and loss becomes r7's
// verified streaming kernel (coalesced NT dwordx4 + exp epilogue, ~40 us).
// Removes loss's two gram passes (~85 us) for ~+20 us of stores + stream.
// ws: [0] Obp packed 4 MB | [4194304] Lnp packed 2 MB | [6291456] sq
//     [6324224] pos_sums | [6356992] neg_sums | [6389760] stats u32[3]
//     [6389824] simT fp16 2080x16384 (68.2 MB) | [74547264] eudT (68.2 MB)

#define B_N 8192
#define NT   64
#define TILE 128
#define NTRI 2080
#define WS_NEEDED 142704704ull

typedef __attribute__((ext_vector_type(8))) short bf16x8;
typedef __attribute__((ext_vector_type(4))) float f32x4;
typedef __attribute__((ext_vector_type(2))) _Float16 f16x2;
typedef __attribute__((ext_vector_type(4))) unsigned u32x4;

typedef const __attribute__((address_space(1))) void g_void;
typedef __attribute__((address_space(3))) void l_void;

__device__ __forceinline__ unsigned fenc(float f) {
    unsigned u = __float_as_uint(f);
    return (u & 0x80000000u) ? ~u : (u | 0x80000000u);
}
__device__ __forceinline__ float fdec(unsigned k) {
    unsigned u = (k & 0x80000000u) ? (k ^ 0x80000000u) : ~k;
    return __uint_as_float(u);
}
__device__ __forceinline__ unsigned pack2(float a, float b) {
    f16x2 p; p[0] = (_Float16)a; p[1] = (_Float16)b;
    return *(unsigned*)&p;
}

// Supertile decode: 4 diagonal 16x16-tri supertiles (136 tiles, b<544),
// then 6 off-diagonal 16x16 supertiles (256 tiles each). bi<=bj always.
__device__ __forceinline__ void tile_decode(int b, int& bi, int& bj) {
    int si, sj, ti, tj;
    if (b < 544) {
        int sb = b / 136, w = b - sb * 136;
        int i = 0;
        while (w >= 16 - i) { w -= 16 - i; i++; }
        si = sb; sj = sb; ti = i; tj = i + w;
    } else {
        int q = (b - 544) >> 8, w = (b - 544) & 255;
        int i = 0;
        while (q >= 3 - i) { q -= 3 - i; i++; }
        si = i; sj = i + 1 + q;
        ti = w >> 4; tj = w & 15;
    }
    bi = si * 16 + ti; bj = sj * 16 + tj;
}

// ---------------------------------------------------------------- prep ----
__global__ __launch_bounds__(256) void prep_kernel(
    const float* __restrict__ outputs, const float* __restrict__ labels,
    __hip_bfloat16* __restrict__ Obp, __hip_bfloat16* __restrict__ Lnp,
    float* __restrict__ sq, float* __restrict__ pos_sums,
    float* __restrict__ neg_sums, unsigned* __restrict__ stats) {
    int g = blockIdx.x, tid = threadIdx.x;
    int rl = tid >> 4, c = tid & 15;
    int row = g * 16 + rl;
    __shared__ __align__(16) short tO[16][264];
    __shared__ __align__(16) short tL[16][136];

    float s = 0.f;
    #pragma unroll
    for (int k = 0; k < 4; k++) {
        f32x4 v = *(const f32x4*)&outputs[(size_t)row * 256 + c * 16 + k * 4];
        s += v[0]*v[0] + v[1]*v[1] + v[2]*v[2] + v[3]*v[3];
        __hip_bfloat16 b4[4];
        #pragma unroll
        for (int i = 0; i < 4; i++) b4[i] = __float2bfloat16(v[i]);
        *(uint2*)&tO[rl][c * 16 + k * 4] = *(uint2*)b4;
    }
    #pragma unroll
    for (int m = 1; m < 16; m <<= 1) s += __shfl_xor(s, m);
    if (c == 0) sq[row] = s;

    float ls = 0.f;
    f32x4 u0 = *(const f32x4*)&labels[(size_t)row * 128 + c * 8];
    f32x4 u1 = *(const f32x4*)&labels[(size_t)row * 128 + c * 8 + 4];
    ls += u0[0]*u0[0] + u0[1]*u0[1] + u0[2]*u0[2] + u0[3]*u0[3];
    ls += u1[0]*u1[0] + u1[1]*u1[1] + u1[2]*u1[2] + u1[3]*u1[3];
    #pragma unroll
    for (int m = 1; m < 16; m <<= 1) ls += __shfl_xor(ls, m);
    float inv = 1.f / (sqrtf(ls) + 1e-12f);
    {
        __hip_bfloat16 b4[4];
        #pragma unroll
        for (int i = 0; i < 4; i++) b4[i] = __float2bfloat16(u0[i] * inv);
        *(uint2*)&tL[rl][c * 8] = *(uint2*)b4;
        #pragma unroll
        for (int i = 0; i < 4; i++) b4[i] = __float2bfloat16(u1[i] * inv);
        *(uint2*)&tL[rl][c * 8 + 4] = *(uint2*)b4;
    }
    if (tid < 16) { pos_sums[g * 16 + tid] = 0.f; neg_sums[g * 16 + tid] = 0.f; }
    if (g == 0 && tid == 0) {
        stats[0] = 0xFFFFFFFFu; stats[1] = 0u; stats[2] = 0u;
    }
    __syncthreads();

    #pragma unroll
    for (int q = 0; q < 2; q++) {
        int sl = tid * 2 + q;
        int o = sl >> 4, rr = sl & 15;
        uint4 d = *(uint4*)&tO[rr][o * 8];
        *(uint4*)&Obp[(size_t)g * 4096 + (size_t)sl * 8] = d;
    }
    {
        int o = tid >> 4, rr = tid & 15;
        uint4 d = *(uint4*)&tL[rr][o * 8];
        *(uint4*)&Lnp[(size_t)g * 2048 + (size_t)tid * 8] = d;
    }
}

// ------------------------------------------------- staged slice gram ----
template<int KD8>
__device__ __forceinline__ void stage_slice(
    const short* __restrict__ P, int g0, int o0, short* L, int tid) {
    #pragma unroll
    for (int p = 0; p < 4; p++) {
        int u = p * 256 + tid;
        int gl = u >> 7, off = u & 127;
        size_t gu = ((size_t)(g0 + gl) * KD8 + o0) * 16 + off;
        __builtin_amdgcn_global_load_lds((g_void*)(P + gu * 8),
                                         (l_void*)(L + (size_t)u * 8), 16, 0, 0);
    }
}

__device__ __forceinline__ void mfma_slice(
    const short* As, const short* Bs, int wm4, int wn4,
    int l15, int quad, f32x4 (&acc)[4][4]) {
    #pragma unroll
    for (int kc = 0; kc < 2; kc++) {
        bf16x8 a[4], b[4];
        #pragma unroll
        for (int mi = 0; mi < 4; mi++)
            a[mi] = *(const bf16x8*)&As[((wm4 + mi) * 128
                                         + (kc * 4 + quad) * 16 + l15) * 8];
        #pragma unroll
        for (int ni = 0; ni < 4; ni++)
            b[ni] = *(const bf16x8*)&Bs[((wn4 + ni) * 128
                                         + (kc * 4 + quad) * 16 + l15) * 8];
        #pragma unroll
        for (int mi = 0; mi < 4; mi++)
            #pragma unroll
            for (int ni = 0; ni < 4; ni++)
                acc[mi][ni] = __builtin_amdgcn_mfma_f32_16x16x32_bf16(
                    a[mi], b[ni], acc[mi][ni], 0, 0, 0);
    }
}

__device__ __forceinline__ void zero_acc(f32x4 (&acc)[4][4]) {
    #pragma unroll
    for (int mi = 0; mi < 4; mi++)
        #pragma unroll
        for (int ni = 0; ni < 4; ni++) {
            f32x4 z = {0.f, 0.f, 0.f, 0.f};
            acc[mi][ni] = z;
        }
}

template<int KD8, int NS>
__device__ __forceinline__ void gram_staged(
    const short* __restrict__ P, int gA0, int gB0,
    short* As, short* Bs, int tid, int wm4, int wn4,
    int l15, int quad, f32x4 (&acc)[4][4]) {
    #pragma unroll
    for (int s = 0; s < NS; s++) {
        __syncthreads();
        stage_slice<KD8>(P, gA0, s * 8, As, tid);
        stage_slice<KD8>(P, gB0, s * 8, Bs, tid);
        __syncthreads();
        mfma_slice(As, Bs, wm4, wn4, l15, quad, acc);
    }
}

// ---------------------------------------------------------------- stats ----
// Staged grams once; min/max/d2max; materializes fp16 sim/eud in the r7
// chunked NT layout: u32 slot = t*8192 + c*1024 + tid*4, c = mi*2 + half.
__global__ __launch_bounds__(256, 2) void stats_kernel(
    const short* __restrict__ Lnp, const short* __restrict__ Obp,
    const float* __restrict__ sq, unsigned* __restrict__ stats,
    unsigned* __restrict__ simT, unsigned* __restrict__ eudT, int store) {
    int bi, bj;
    tile_decode(blockIdx.x, bi, bj);
    int tid = threadIdx.x, lane = tid & 63, wid = tid >> 6;
    int wm = (wid >> 1) * 64, wn = (wid & 1) * 64;
    int wm4 = (wid >> 1) * 4, wn4 = (wid & 1) * 4;
    int l15 = lane & 15, quad = lane >> 4;
    int rB = bi * TILE, cB = bj * TILE;
    size_t tB = (size_t)blockIdx.x * 8192 + (size_t)tid * 4;

    __shared__ __align__(16) short As[1024 * 8];
    __shared__ __align__(16) short Bs[1024 * 8];

    float lmin = 1e30f, lmax = -1e30f, dmax = 0.f;
    f32x4 acc[4][4];

    zero_acc(acc);
    gram_staged<16, 2>(Lnp, bi * 8, bj * 8, As, Bs, tid, wm4, wn4, l15, quad, acc);
    #pragma unroll
    for (int mi = 0; mi < 4; mi++) {
        u32x4 v0, v1;
        #pragma unroll
        for (int ni = 0; ni < 4; ni++)
            #pragma unroll
            for (int h = 0; h < 2; h++) {
                float s0 = acc[mi][ni][2 * h], s1 = acc[mi][ni][2 * h + 1];
                lmin = fminf(lmin, fminf(s0, s1));
                lmax = fmaxf(lmax, fmaxf(s0, s1));
                int j = ni * 2 + h;
                unsigned pk = pack2(s0, s1);
                if (j < 4) v0[j] = pk; else v1[j - 4] = pk;
            }
        if (store) {
            __builtin_nontemporal_store(v0, (u32x4*)(simT + tB + (mi * 2 + 0) * 1024));
            __builtin_nontemporal_store(v1, (u32x4*)(simT + tB + (mi * 2 + 1) * 1024));
        }
    }

    zero_acc(acc);
    gram_staged<32, 4>(Obp, bi * 8, bj * 8, As, Bs, tid, wm4, wn4, l15, quad, acc);
    float sqj[4];
    #pragma unroll
    for (int ni = 0; ni < 4; ni++) sqj[ni] = sq[cB + wn + ni * 16 + l15];
    #pragma unroll
    for (int mi = 0; mi < 4; mi++) {
        f32x4 sqi = *(const f32x4*)&sq[rB + wm + mi * 16 + quad * 4];
        u32x4 v0, v1;
        #pragma unroll
        for (int ni = 0; ni < 4; ni++)
            #pragma unroll
            for (int h = 0; h < 2; h++) {
                float d20 = fmaxf(sqi[2*h]   + sqj[ni] - 2.f * acc[mi][ni][2*h],   0.f);
                float d21 = fmaxf(sqi[2*h+1] + sqj[ni] - 2.f * acc[mi][ni][2*h+1], 0.f);
                dmax = fmaxf(dmax, fmaxf(d20, d21));
                float e0 = (d20 > 0.f) ? sqrtf(d20) : 0.f;
                float e1 = (d21 > 0.f) ? sqrtf(d21) : 0.f;
                int j = ni * 2 + h;
                unsigned pk = pack2(e0, e1);
                if (j < 4) v0[j] = pk; else v1[j - 4] = pk;
            }
        if (store) {
            __builtin_nontemporal_store(v0, (u32x4*)(eudT + tB + (mi * 2 + 0) * 1024));
            __builtin_nontemporal_store(v1, (u32x4*)(eudT + tB + (mi * 2 + 1) * 1024));
        }
    }

    #pragma unroll
    for (int m = 1; m < 64; m <<= 1) {
        lmin = fminf(lmin, __shfl_xor(lmin, m));
        lmax = fmaxf(lmax, __shfl_xor(lmax, m));
        dmax = fmaxf(dmax, __shfl_xor(dmax, m));
    }
    __shared__ float red[3][4];
    if ((tid & 63) == 0) { red[0][wid] = lmin; red[1][wid] = lmax; red[2][wid] = dmax; }
    __syncthreads();
    if (tid == 0) {
        lmin = fminf(fminf(red[0][0], red[0][1]), fminf(red[0][2], red[0][3]));
        lmax = fmaxf(fmaxf(red[1][0], red[1][1]), fmaxf(red[1][2], red[1][3]));
        dmax = fmaxf(fmaxf(red[2][0], red[2][1]), fmaxf(red[2][2], red[2][3]));
        atomicMin(&stats[0], fenc(lmin));
        atomicMax(&stats[1], fenc(lmax));
        atomicMax(&stats[2], fenc(dmax));
    }
}

// ----------------------------------------------------------- loss stream ----
// Pure streaming epilogue (r7-verified): coalesced NT dwordx4 reads,
// exp terms, row+col sums, one atomic per row per block.
__global__ __launch_bounds__(256) void loss_stream_kernel(
    const unsigned* __restrict__ simT, const unsigned* __restrict__ eudT,
    const unsigned* __restrict__ stats,
    float* __restrict__ pos_sums, float* __restrict__ neg_sums) {
    int bi, bj;
    tile_decode(blockIdx.x, bi, bj);
    int tid = threadIdx.x, lane = tid & 63, wid = tid >> 6;
    int wm = (wid >> 1) * 64, wn = (wid & 1) * 64;
    int l15 = lane & 15, quad = lane >> 4;
    size_t tB = (size_t)blockIdx.x * 8192 + (size_t)tid * 4;

    float smin = fdec(stats[0]);
    float smax = fdec(stats[1]);
    float d2max = fdec(stats[2]);
    float invr = 1.f / (smax - smin);
    float invem = rsqrtf(d2max);

    __shared__ float rP[TILE][2], rN[TILE][2];
    __shared__ float cP[TILE][2], cN[TILE][2];
    float cpsum[4] = {0.f, 0.f, 0.f, 0.f};
    float cnsum[4] = {0.f, 0.f, 0.f, 0.f};

    #pragma unroll
    for (int mi = 0; mi < 4; mi++) {
        u32x4 s0 = __builtin_nontemporal_load((const u32x4*)(simT + tB + (mi * 2 + 0) * 1024));
        u32x4 s1 = __builtin_nontemporal_load((const u32x4*)(simT + tB + (mi * 2 + 1) * 1024));
        u32x4 e0 = __builtin_nontemporal_load((const u32x4*)(eudT + tB + (mi * 2 + 0) * 1024));
        u32x4 e1 = __builtin_nontemporal_load((const u32x4*)(eudT + tB + (mi * 2 + 1) * 1024));
        float ps[4] = {0.f, 0.f, 0.f, 0.f};
        float ns[4] = {0.f, 0.f, 0.f, 0.f};
        #pragma unroll
        for (int j = 0; j < 8; j++) {
            unsigned sv = (j < 4) ? s0[j] : s1[j - 4];
            unsigned ev = (j < 4) ? e0[j] : e1[j - 4];
            int ni = j >> 1, h = j & 1;
            f16x2 spair = *(f16x2*)&sv;
            f16x2 epair = *(f16x2*)&ev;
            #pragma unroll
            for (int e = 0; e < 2; e++) {
                float sn = ((float)spair[e] - smin) * invr;
                float dist = (float)epair[e] * invem + sn;
                bool pos = sn > 0.5f;   // TAU
                float pv = pos ? __expf(dist) : 0.f;
                float nv = pos ? 0.f : __expf(1.0f - dist);  // MAG = 1
                ps[2 * h + e] += pv;  ns[2 * h + e] += nv;
                cpsum[ni] += pv;  cnsum[ni] += nv;
            }
        }
        #pragma unroll
        for (int r = 0; r < 4; r++) {
            #pragma unroll
            for (int m = 1; m < 16; m <<= 1) {
                ps[r] += __shfl_xor(ps[r], m);
                ns[r] += __shfl_xor(ns[r], m);
            }
            if (l15 == 0) {
                int rr = wm + mi * 16 + quad * 4 + r;
                rP[rr][wid & 1] = ps[r];
                rN[rr][wid & 1] = ns[r];
            }
        }
    }
    #pragma unroll
    for (int ni = 0; ni < 4; ni++) {
        #pragma unroll
        for (int m = 16; m < 64; m <<= 1) {
            cpsum[ni] += __shfl_xor(cpsum[ni], m);
            cnsum[ni] += __shfl_xor(cnsum[ni], m);
        }
        if (quad == 0) {
            int cc = wn + ni * 16 + l15;
            cP[cc][wid >> 1] = cpsum[ni];
            cN[cc][wid >> 1] = cnsum[ni];
        }
    }
    __syncthreads();
    if (tid < TILE) {
        atomicAdd(&pos_sums[bi * TILE + tid], rP[tid][0] + rP[tid][1]);
        atomicAdd(&neg_sums[bi * TILE + tid], rN[tid][0] + rN[tid][1]);
        if (bi != bj) {
            atomicAdd(&pos_sums[bj * TILE + tid], cP[tid][0] + cP[tid][1]);
            atomicAdd(&neg_sums[bj * TILE + tid], cN[tid][0] + cN[tid][1]);
        }
    }
}

// ------------------------------------------ loss fallback (recompute, r18) ----
__global__ __launch_bounds__(256, 2) void loss_recompute_kernel(
    const short* __restrict__ Lnp, const short* __restrict__ Obp,
    const float* __restrict__ sq, const unsigned* __restrict__ stats,
    float* __restrict__ pos_sums, float* __restrict__ neg_sums) {
    int bi, bj;
    tile_decode(blockIdx.x, bi, bj);
    int tid = threadIdx.x, lane = tid & 63, wid = tid >> 6;
    int wm = (wid >> 1) * 64, wn = (wid & 1) * 64;
    int wm4 = (wid >> 1) * 4, wn4 = (wid & 1) * 4;
    int l15 = lane & 15, quad = lane >> 4;
    int rB = bi * TILE, cB = bj * TILE;

    __shared__ __align__(16) short As[1024 * 8];
    __shared__ __align__(16) short Bs[1024 * 8];
    __shared__ unsigned simW[256 * 33];
    __shared__ float rP[TILE][2], rN[TILE][2];
    __shared__ float cP[TILE][2], cN[TILE][2];
    unsigned* my = &simW[tid * 33];

    f32x4 acc[4][4];

    zero_acc(acc);
    gram_staged<16, 2>(Lnp, bi * 8, bj * 8, As, Bs, tid, wm4, wn4, l15, quad, acc);
    #pragma unroll
    for (int mi = 0; mi < 4; mi++)
        #pragma unroll
        for (int ni = 0; ni < 4; ni++) {
            my[(mi * 4 + ni) * 2 + 0] = pack2(acc[mi][ni][0], acc[mi][ni][1]);
            my[(mi * 4 + ni) * 2 + 1] = pack2(acc[mi][ni][2], acc[mi][ni][3]);
        }

    zero_acc(acc);
    gram_staged<32, 4>(Obp, bi * 8, bj * 8, As, Bs, tid, wm4, wn4, l15, quad, acc);

    float smin = fdec(stats[0]);
    float smax = fdec(stats[1]);
    float d2max = fdec(stats[2]);
    float invr = 1.f / (smax - smin);
    float invem = rsqrtf(d2max);

    float sqj[4];
    #pragma unroll
    for (int ni = 0; ni < 4; ni++) sqj[ni] = sq[cB + wn + ni * 16 + l15];
    float cpsum[4] = {0.f, 0.f, 0.f, 0.f};
    float cnsum[4] = {0.f, 0.f, 0.f, 0.f};

    #pragma unroll
    for (int mi = 0; mi < 4; mi++) {
        f32x4 sqi = *(const f32x4*)&sq[rB + wm + mi * 16 + quad * 4];
        float ps[4] = {0.f, 0.f, 0.f, 0.f};
        float ns[4] = {0.f, 0.f, 0.f, 0.f};
        #pragma unroll
        for (int ni = 0; ni < 4; ni++) {
            f16x2 s01 = ((const f16x2*)my)[(mi * 4 + ni) * 2 + 0];
            f16x2 s23 = ((const f16x2*)my)[(mi * 4 + ni) * 2 + 1];
            #pragma unroll
            for (int r = 0; r < 4; r++) {
                float sraw = (r < 2) ? (float)s01[r] : (float)s23[r - 2];
                float sn = (sraw - smin) * invr;
                float g = acc[mi][ni][r];
                float d2 = fmaxf(sqi[r] + sqj[ni] - 2.f * g, 0.f);
                float eud = (d2 > 0.f) ? sqrtf(d2) * invem : 0.f;
                float dist = eud + sn;
                bool pos = sn > 0.5f;
                float pv = pos ? __expf(dist) : 0.f;
                float nv = pos ? 0.f : __expf(1.0f - dist);
                ps[r] += pv;  ns[r] += nv;
                cpsum[ni] += pv;  cnsum[ni] += nv;
            }
        }
        #pragma unroll
        for (int r = 0; r < 4; r++) {
            #pragma unroll
            for (int m = 1; m < 16; m <<= 1) {
                ps[r] += __shfl_xor(ps[r], m);
                ns[r] += __shfl_xor(ns[r], m);
            }
            if (l15 == 0) {
                int rr = wm + mi * 16 + quad * 4 + r;
                rP[rr][wid & 1] = ps[r];
                rN[rr][wid & 1] = ns[r];
            }
        }
    }
    #pragma unroll
    for (int ni = 0; ni < 4; ni++) {
        #pragma unroll
        for (int m = 16; m < 64; m <<= 1) {
            cpsum[ni] += __shfl_xor(cpsum[ni], m);
            cnsum[ni] += __shfl_xor(cnsum[ni], m);
        }
        if (quad == 0) {
            int cc = wn + ni * 16 + l15;
            cP[cc][wid >> 1] = cpsum[ni];
            cN[cc][wid >> 1] = cnsum[ni];
        }
    }
    __syncthreads();
    if (tid < TILE) {
        atomicAdd(&pos_sums[bi * TILE + tid], rP[tid][0] + rP[tid][1]);
        atomicAdd(&neg_sums[bi * TILE + tid], rN[tid][0] + rN[tid][1]);
        if (bi != bj) {
            atomicAdd(&pos_sums[bj * TILE + tid], cP[tid][0] + cP[tid][1]);
            atomicAdd(&neg_sums[bj * TILE + tid], cN[tid][0] + cN[tid][1]);
        }
    }
}

// ------------------------------------------------------------- finalize ----
__global__ __launch_bounds__(256) void finalize_kernel(
    const float* __restrict__ pos_sums, const float* __restrict__ neg_sums,
    float* __restrict__ out) {
    int t = threadIdx.x;
    float acc = 0.f;
    for (int i = t; i < B_N; i += 256) {
        float p = pos_sums[i], n = neg_sums[i];
        float pl = fmaxf(logf(p), 0.f);
        float nl = (n > 0.f) ? fmaxf(logf(n), 0.f) : 0.f;
        acc += pl + nl;
    }
    #pragma unroll
    for (int m = 1; m < 64; m <<= 1) acc += __shfl_xor(acc, m);
    __shared__ float w4[4];
    if ((t & 63) == 0) w4[t >> 6] = acc;
    __syncthreads();
    if (t == 0) out[0] = (w4[0] + w4[1] + w4[2] + w4[3]) / (float)B_N;
}

// ------------------------------------------------------------------ entry ----
extern "C" void kernel_launch(void* const* d_in, const int* in_sizes, int n_in,
                              void* d_out, int out_size, void* d_ws, size_t ws_size,
                              hipStream_t stream) {
    const float* outputs = (const float*)d_in[0];
    const float* labels  = (const float*)d_in[1];
    float* out = (float*)d_out;
    char* ws = (char*)d_ws;
    __hip_bfloat16* Obp = (__hip_bfloat16*)(ws);
    __hip_bfloat16* Lnp = (__hip_bfloat16*)(ws + 4194304);
    float* sq           = (float*)(ws + 6291456);
    float* pos_sums     = (float*)(ws + 6324224);
    float* neg_sums     = (float*)(ws + 6356992);
    unsigned* stats     = (unsigned*)(ws + 6389760);
    unsigned* simT      = (unsigned*)(ws + 6389824);
    unsigned* eudT      = (unsigned*)(ws + 74547264);
    int big = (ws_size >= WS_NEEDED) ? 1 : 0;

    prep_kernel<<<B_N / 16, 256, 0, stream>>>(outputs, labels, Obp, Lnp, sq,
                                              pos_sums, neg_sums, stats);
    stats_kernel<<<NTRI, 256, 0, stream>>>((const short*)Lnp, (const short*)Obp,
                                           sq, stats, simT, eudT, big);
    if (big)
        loss_stream_kernel<<<NTRI, 256, 0, stream>>>(simT, eudT, stats,
                                                     pos_sums, neg_sums);
    else
        loss_recompute_kernel<<<NTRI, 256, 0, stream>>>((const short*)Lnp,
                                                        (const short*)Obp,
                                                        sq, stats,
                                                        pos_sums, neg_sums);
    finalize_kernel<<<1, 256, 0, stream>>>(pos_sums, neg_sums, out);
}